// Round 15
// baseline (184.584 us; speedup 1.0000x reference)
//
#include <hip/hip_runtime.h>
#include <hip/hip_bf16.h>

#define NN 4096
#define DD 128
#define NS 75
#define TOT (NN * NN)

// k_d2 tiling (MFMA): 128x128 block, 4 waves, 64x64 per wave
#define BT 128
#define NBD2 (NN / BT)                      // 32
#define GRID_D2 (NBD2 * (NBD2 + 1) / 2)     // 528

// sweep tiling: 8-row x 512-col strips over upper triangle
#define SW_H 8
#define SW_W 512
#define NSTRIP (NN / SW_H)                  // 512
#define NCT (NN / SW_W)                     // 8
#define GRID_SW 2304                        // sum_s (8 - s/64) = 4096 - 64*28

typedef float v2f __attribute__((ext_vector_type(2)));
typedef float f32x4 __attribute__((ext_vector_type(4)));
typedef short bf16x8 __attribute__((ext_vector_type(8)));

#define NEG_INF (-__builtin_inff())

__device__ __forceinline__ float fexp2(float v) { return __builtin_amdgcn_exp2f(v); }

// DPP lane-shift add: no LDS/ds_bpermute latency (register-file crossing, ~2cy).
template <int CTRL>
__device__ __forceinline__ float dpp_add(float x) {
    int y = __builtin_amdgcn_update_dpp(0, __float_as_int(x), CTRL, 0xf, 0xf, true);
    return x + __int_as_float(y);
}
// Full wave64 sum; result lands in lane 63. Canonical gfx9 sequence.
__device__ __forceinline__ float wave_sum(float x) {
    x = dpp_add<0x111>(x);   // row_shr:1
    x = dpp_add<0x112>(x);   // row_shr:2
    x = dpp_add<0x114>(x);   // row_shr:4
    x = dpp_add<0x118>(x);   // row_shr:8
    x = dpp_add<0x142>(x);   // row_bcast:15
    x = dpp_add<0x143>(x);   // row_bcast:31 -> lane63 = wave sum
    return x;
}

// linear index -> (bi, bj) with bi <= bj, row-major over upper triangle
__device__ __forceinline__ void tri_decode(int t, int nb, int& bi, int& bj) {
    int b = 0, rem = t;
    while (rem >= nb - b) { rem -= nb - b; ++b; }
    bi = b; bj = b + rem;
}

// sweep strip decode: strips grouped by j_min = s>>6 (g=0..7); per strip in
// group g there are 8-g col-tiles (j = g..7).
__device__ __forceinline__ void strip_decode(int t, int& s, int& j) {
    int g = 0, off = 0;
    while (true) {
        int cnt = 64 * (8 - g);
        if (t - off < cnt) break;
        off += cnt; ++g;
    }
    int rem = t - off, c = 8 - g;
    s = 64 * g + rem / c;
    j = g + rem % c;
}

// Split f32 -> bf16 hi + bf16 lo (exact residual truncated).
__device__ __forceinline__ void cvt_split(const float4& v0, const float4& v1,
                                          bf16x8& hi, bf16x8& lo) {
    float f[8] = {v0.x, v0.y, v0.z, v0.w, v1.x, v1.y, v1.z, v1.w};
#pragma unroll
    for (int j = 0; j < 8; ++j) {
        unsigned b = __float_as_uint(f[j]);
        hi[j] = (short)(b >> 16);
        float l = f[j] - __uint_as_float(b & 0xFFFF0000u);
        lo[j] = (short)(__float_as_uint(l) >> 16);
    }
}

// Coarse argmax over slots 0..24 (stride-3 sigmas) -> refine window base.
__device__ __forceinline__ int coarse_window(const double* KL, const double* KK) {
    double best = -1.0;
    int bk = 0;
    for (int k = 0; k < 25; ++k) {
        double loss = KL[k] / sqrt(KK[k]);
        if (loss > best) { best = loss; bk = k; }   // strict > = first max
    }
    int wv = 3 * bk - 2;
    if (wv < 0) wv = 0;
    if (wv > NS - 5) wv = NS - 5;
    return wv;
}

// ---------------- ws layout (bytes) ----------------
// KL/KK: slots 0..25 coarse (25 used + 1 dup), 26..30 refine.
#define WS_DSUM 0                      // double
#define WS_NZC  8                      // unsigned long long
#define WS_KL   16                     // double[32]
#define WS_KK   (16 + 256)             // double[32]
#define WS_SQ   (16 + 512)             // float[NN]
#define WS_CSIG (WS_SQ + 4 * NN)       // float[NS]

__global__ void k_rowsq(const float* __restrict__ x, float* __restrict__ sq,
                        double* __restrict__ dsum, unsigned long long* __restrict__ nzc) {
    int tid = blockIdx.x * blockDim.x + threadIdx.x;
    if (tid == 0) { *dsum = 0.0; *nzc = 0ull; }
    if (tid < NN) {
        const float4* row = (const float4*)(x + (size_t)tid * DD);
        float s = 0.f;
#pragma unroll
        for (int i = 0; i < DD / 4; ++i) {
            float4 v = row[i];
            s += v.x * v.x + v.y * v.y + v.z * v.z + v.w * v.w;
        }
        sq[tid] = s;
    }
}

// d2 via split-bf16 MFMA. Upper-tri 128-blocks only, NO mirror writes:
// below-diag d2 is never read (sweeps mask it; final mirrors from upper).
__launch_bounds__(256)
__global__ void k_d2(const float* __restrict__ x, const float* __restrict__ sq,
                     float* __restrict__ d2, double* __restrict__ dsum,
                     unsigned long long* __restrict__ nzc) {
    __shared__ double red_d[4];
    __shared__ int red_n[4];

    int bi, bj;
    tri_decode(blockIdx.x, NBD2, bi, bj);
    const int r0 = bi * BT, c0 = bj * BT;
    const int tid = threadIdx.x;
    const int l  = tid & 63, wid = tid >> 6;
    const int wr = wid >> 1, wc = wid & 1;
    const int lr = l & 15;
    const int lk = (l >> 4) * 8;
    const int l4 = (l >> 4) * 4;

    const int ar = r0 + wr * 64 + lr;
    const int br = c0 + wc * 64 + lr;

    f32x4 acc[4][4];
#pragma unroll
    for (int a = 0; a < 4; ++a)
#pragma unroll
        for (int b = 0; b < 4; ++b) acc[a][b] = (f32x4){0.f, 0.f, 0.f, 0.f};

#pragma unroll 1
    for (int kc = 0; kc < 4; ++kc) {
        const int k0 = kc * 32 + lk;
        bf16x8 ah[4], al[4], bh[4], bl[4];
#pragma unroll
        for (int t = 0; t < 4; ++t) {
            const float* pa = x + (size_t)(ar + t * 16) * DD + k0;
            float4 a0 = *(const float4*)pa;
            float4 a1 = *(const float4*)(pa + 4);
            cvt_split(a0, a1, ah[t], al[t]);
            const float* pb = x + (size_t)(br + t * 16) * DD + k0;
            float4 b0 = *(const float4*)pb;
            float4 b1 = *(const float4*)(pb + 4);
            cvt_split(b0, b1, bh[t], bl[t]);
        }
#pragma unroll
        for (int a = 0; a < 4; ++a)
#pragma unroll
            for (int b = 0; b < 4; ++b) {
                acc[a][b] = __builtin_amdgcn_mfma_f32_16x16x32_bf16(ah[a], bh[b], acc[a][b], 0, 0, 0);
                acc[a][b] = __builtin_amdgcn_mfma_f32_16x16x32_bf16(ah[a], bl[b], acc[a][b], 0, 0, 0);
                acc[a][b] = __builtin_amdgcn_mfma_f32_16x16x32_bf16(al[a], bh[b], acc[a][b], 0, 0, 0);
            }
    }

    float myd = 0.f;
    int myn = 0;
#pragma unroll
    for (int a = 0; a < 4; ++a) {
        const int grb = r0 + wr * 64 + a * 16 + l4;
        float4 sqr = *(const float4*)(sq + grb);
        float sr[4] = {sqr.x, sqr.y, sqr.z, sqr.w};
#pragma unroll
        for (int b = 0; b < 4; ++b) {
            const int gc = c0 + wc * 64 + b * 16 + lr;
            const float sc = sq[gc];
#pragma unroll
            for (int v = 0; v < 4; ++v) {
                float d = fmaxf(sr[v] + sc - 2.f * acc[a][b][v], 0.f);
                if (d > 0.f) { myd += sqrtf(d); ++myn; }
                d2[(size_t)(grb + v) * NN + gc] = d;
            }
        }
    }

    const int w = (bi == bj) ? 1 : 2;
    float sd = wave_sum(myd);
    float sn = wave_sum((float)myn);
    if ((tid & 63) == 63) { red_d[wid] = (double)sd; red_n[wid] = (int)sn; }
    __syncthreads();
    if (tid == 0) {
        double td = red_d[0] + red_d[1] + red_d[2] + red_d[3];
        int tn = red_n[0] + red_n[1] + red_n[2] + red_n[3];
        atomicAdd(dsum, td * (double)w);
        atomicAdd(nzc, (unsigned long long)(tn * w));
    }
}

// KL/KK init = 4096: the diagonal's analytic contribution (d2_ii ~ 0 -> K=1;
// lk_ii = 1), excluded from the sweeps via the -inf mask.
__global__ void k_sigmas(const double* __restrict__ dsum, const unsigned long long* __restrict__ nzc,
                         float* __restrict__ csig, double* __restrict__ KL, double* __restrict__ KK) {
    int t = threadIdx.x;
    float mean = (float)(*dsum / (double)(*nzc));
    float lo = 0.1f * mean;
    float hi = 10.0f * mean;
    float step = (hi - lo) / (float)NS;
    if (t < NS) {
        float s = lo + step * (float)t;
        csig[t] = (float)(1.4426950408889634 / ((double)s * (double)s));
    }
    if (t < 32) { KL[t] = 4096.0; KK[t] = 4096.0; }
}

// Load a thread's 16 elems of the 8x512 strip tile; elements with col<=row
// (diag + below) masked to nd=-inf (exp2 -> 0). 2KB contiguous per row.
__device__ __forceinline__ void sweep_load(const float* __restrict__ d2,
                                           const float* __restrict__ lk,
                                           int s, int j, v2f* nd, v2f* ll) {
    const int row  = s * SW_H + (threadIdx.x >> 5);
    const int col0 = j * SW_W + (threadIdx.x & 31) * 16;
    const size_t base = (size_t)row * NN + col0;
#pragma unroll
    for (int q = 0; q < 4; ++q) {
        float4 dv = *(const float4*)(d2 + base + q * 4);
        float4 lv = *(const float4*)(lk + base + q * 4);
        const int c = col0 + q * 4;
        float n0 = (c + 0 > row) ? -dv.x : NEG_INF;
        float n1 = (c + 1 > row) ? -dv.y : NEG_INF;
        float n2 = (c + 2 > row) ? -dv.z : NEG_INF;
        float n3 = (c + 3 > row) ? -dv.w : NEG_INF;
        nd[q * 2 + 0] = (v2f){n0, n1};
        nd[q * 2 + 1] = (v2f){n2, n3};
        ll[q * 2 + 0] = (v2f){lv.x, lv.y};
        ll[q * 2 + 1] = (v2f){lv.z, lv.w};
    }
}

// Coarse: 25 stride-3 sigmas (+1 dup), chunk loop CH=13 x 2 (R11's proven
// register shape). Weight 2 applied at atomic; diag handled in init.
__launch_bounds__(256, 3)
__global__ void k_sweep_coarse(const float* __restrict__ d2, const float* __restrict__ lk,
                               const float* __restrict__ csig, double* __restrict__ KL,
                               double* __restrict__ KK) {
    int s, j;
    strip_decode(blockIdx.x, s, j);

    v2f nd[8], ll[8];
    sweep_load(d2, lk, s, j, nd, ll);

    __shared__ double part[4][52];
    const int lane = threadIdx.x & 63, wave = threadIdx.x >> 6;

#pragma unroll 1
    for (int ch = 0; ch < 2; ++ch) {
        float c[13];
#pragma unroll
        for (int q = 0; q < 13; ++q) {
            int i = ch * 13 + q;
            int ci = i > 24 ? 24 : i;      // slot 25 duplicates 24 (ignored)
            c[q] = __int_as_float(__builtin_amdgcn_readfirstlane(
                       __float_as_int(csig[3 * ci])));
        }
        v2f akl[13], akk[13];
#pragma unroll
        for (int q = 0; q < 13; ++q) { akl[q] = (v2f){0.f, 0.f}; akk[q] = (v2f){0.f, 0.f}; }

#pragma unroll
        for (int e = 0; e < 8; ++e) {
            v2f ndv = nd[e], L = ll[e];
#pragma unroll
            for (int q = 0; q < 13; ++q) {
                v2f arg = ndv * c[q];                               // v_pk_mul_f32
                v2f K = {fexp2(arg.x), fexp2(arg.y)};               // 2x v_exp_f32
                akl[q] = __builtin_elementwise_fma(K, L, akl[q]);   // v_pk_fma_f32
                akk[q] = __builtin_elementwise_fma(K, K, akk[q]);
            }
        }

#pragma unroll
        for (int q = 0; q < 13; ++q) {
            float v1 = wave_sum(akl[q].x + akl[q].y);
            float v2 = wave_sum(akk[q].x + akk[q].y);
            if (lane == 63) {
                part[wave][ch * 13 + q]      = (double)v1;
                part[wave][26 + ch * 13 + q] = (double)v2;
            }
        }
    }
    __syncthreads();
    const int t = threadIdx.x;
    if (t < 52) {
        double v = 2.0 * (part[0][t] + part[1][t] + part[2][t] + part[3][t]);
        if (t < 26) atomicAdd(&KL[t], v);
        else        atomicAdd(&KK[t - 26], v);
    }
}

// Refine: window recomputed per block (deterministic), 5 stride-1 sigmas,
// slots 26..30.
__launch_bounds__(256, 3)
__global__ void k_sweep_refine(const float* __restrict__ d2, const float* __restrict__ lk,
                               const float* __restrict__ csig, double* __restrict__ KL,
                               double* __restrict__ KK) {
    __shared__ int w0_sh;
    if (threadIdx.x == 0) w0_sh = coarse_window(KL, KK);
    __syncthreads();
    const int s0 = w0_sh;

    int s, j;
    strip_decode(blockIdx.x, s, j);

    v2f nd[8], ll[8];
    sweep_load(d2, lk, s, j, nd, ll);

    __shared__ double part[4][10];
    const int lane = threadIdx.x & 63, wave = threadIdx.x >> 6;

    float c[5];
#pragma unroll
    for (int q = 0; q < 5; ++q)
        c[q] = __int_as_float(__builtin_amdgcn_readfirstlane(
                   __float_as_int(csig[s0 + q])));
    v2f akl[5], akk[5];
#pragma unroll
    for (int q = 0; q < 5; ++q) { akl[q] = (v2f){0.f, 0.f}; akk[q] = (v2f){0.f, 0.f}; }

#pragma unroll
    for (int e = 0; e < 8; ++e) {
        v2f ndv = nd[e], L = ll[e];
#pragma unroll
        for (int q = 0; q < 5; ++q) {
            v2f arg = ndv * c[q];
            v2f K = {fexp2(arg.x), fexp2(arg.y)};
            akl[q] = __builtin_elementwise_fma(K, L, akl[q]);
            akk[q] = __builtin_elementwise_fma(K, K, akk[q]);
        }
    }

#pragma unroll
    for (int q = 0; q < 5; ++q) {
        float v1 = wave_sum(akl[q].x + akl[q].y);
        float v2 = wave_sum(akk[q].x + akk[q].y);
        if (lane == 63) { part[wave][q] = (double)v1; part[wave][5 + q] = (double)v2; }
    }
    __syncthreads();
    const int t = threadIdx.x;
    if (t < 10) {
        double v = 2.0 * (part[0][t] + part[1][t] + part[2][t] + part[3][t]);
        if (t < 5) atomicAdd(&KL[26 + t], v);
        else       atomicAdd(&KK[26 + t - 5], v);
    }
}

// Final: recompute copt per block (coarse window + refine argmax over slots
// 26..30), then A = exp2(-d2*c)/n over upper-tri blocks with mirror writes.
__launch_bounds__(256)
__global__ void k_final(float* __restrict__ d2, const double* __restrict__ KL,
                        const double* __restrict__ KK, const float* __restrict__ csig) {
    __shared__ float cc_sh;
    if (threadIdx.x == 0) {
        int wv = coarse_window(KL, KK);
        double best = -1.0;
        int bk = 0;
        for (int k = 0; k < 5; ++k) {
            double loss = KL[26 + k] / sqrt(KK[26 + k]);
            if (loss > best) { best = loss; bk = k; }
        }
        cc_sh = csig[wv + bk];
    }
    __syncthreads();
    const float cc = cc_sh;
    const float inv_n = 1.0f / (float)NN;

    int bi, bj;
    tri_decode(blockIdx.x, NBD2, bi, bj);
    const int r0 = bi * BT, c0 = bj * BT;
    const int tx = threadIdx.x & 31, ty = threadIdx.x >> 5;

    float a[16][4];
#pragma unroll
    for (int r = 0; r < 16; ++r) {
        size_t off = (size_t)(r0 + ty * 16 + r) * NN + c0 + tx * 4;
        float4 v = *(const float4*)(d2 + off);
        a[r][0] = fexp2(-v.x * cc) * inv_n;
        a[r][1] = fexp2(-v.y * cc) * inv_n;
        a[r][2] = fexp2(-v.z * cc) * inv_n;
        a[r][3] = fexp2(-v.w * cc) * inv_n;
        float4 o = {a[r][0], a[r][1], a[r][2], a[r][3]};
        *(float4*)(d2 + off) = o;
    }
    if (bi != bj) {
#pragma unroll
        for (int c = 0; c < 4; ++c) {
            size_t base = (size_t)(c0 + tx * 4 + c) * NN + r0 + ty * 16;
            float4 w0 = {a[0][c],  a[1][c],  a[2][c],  a[3][c]};
            float4 w1 = {a[4][c],  a[5][c],  a[6][c],  a[7][c]};
            float4 w2 = {a[8][c],  a[9][c],  a[10][c], a[11][c]};
            float4 w3 = {a[12][c], a[13][c], a[14][c], a[15][c]};
            *(float4*)(d2 + base + 0)  = w0;
            *(float4*)(d2 + base + 4)  = w1;
            *(float4*)(d2 + base + 8)  = w2;
            *(float4*)(d2 + base + 12) = w3;
        }
    }
}

extern "C" void kernel_launch(void* const* d_in, const int* in_sizes, int n_in,
                              void* d_out, int out_size, void* d_ws, size_t ws_size,
                              hipStream_t stream) {
    const float* x  = (const float*)d_in[0];
    const float* lk = (const float*)d_in[1];
    float* out = (float*)d_out;   // doubles as the d2 buffer, transformed in place at the end
    char* ws = (char*)d_ws;

    double* dsum = (double*)(ws + WS_DSUM);
    unsigned long long* nzc = (unsigned long long*)(ws + WS_NZC);
    double* KL = (double*)(ws + WS_KL);
    double* KK = (double*)(ws + WS_KK);
    float* sqv  = (float*)(ws + WS_SQ);
    float* csig = (float*)(ws + WS_CSIG);

    hipLaunchKernelGGL(k_rowsq, dim3(NN / 256), dim3(256), 0, stream, x, sqv, dsum, nzc);
    hipLaunchKernelGGL(k_d2, dim3(GRID_D2), dim3(256), 0, stream, x, sqv, out, dsum, nzc);
    hipLaunchKernelGGL(k_sigmas, dim3(1), dim3(128), 0, stream, dsum, nzc, csig, KL, KK);
    hipLaunchKernelGGL(k_sweep_coarse, dim3(GRID_SW), dim3(256), 0, stream, out, lk, csig, KL, KK);
    hipLaunchKernelGGL(k_sweep_refine, dim3(GRID_SW), dim3(256), 0, stream, out, lk, csig, KL, KK);
    hipLaunchKernelGGL(k_final, dim3(GRID_D2), dim3(256), 0, stream, out, KL, KK, csig);
}